// Round 4
// baseline (135.821 us; speedup 1.0000x reference)
//
#include <hip/hip_runtime.h>
#include <hip/hip_bf16.h>

typedef unsigned short u16;
typedef __attribute__((ext_vector_type(8))) short short8;
typedef __attribute__((ext_vector_type(4))) float f32x4;
typedef __attribute__((ext_vector_type(4))) unsigned int u32x4;

#define CC    128
#define WW    48
#define HW2   2304      // 48*48
#define NHW   46
#define NQ    2116      // 46*46
#define MROWS 2176      // padded M rows per batch (17*128)
#define NPK   2176      // rows per candidate set inside B
#define NTOT  4352      // 17*256
#define KK    1152      // 128*9
#define NKT   18        // K-tiles of 64
#define NHALF 68        // 17 N-tiles * 4 wave-columns
#define BATCH 2

__device__ __forceinline__ u16 f2bf(float f) {
  union { float f; unsigned u; } x; x.f = f;
  unsigned r = (x.u + 0x7fffu + ((x.u >> 16) & 1u)) >> 16;
  return (u16)r;
}

// ---- kernel 1: fused invnorm + im2col (bf16, pre-swizzled chunks), LDS-staged ----
// Row r holds K=1152 bf16 = 144 16B-chunks. Within each aligned 8-chunk group,
// stored position p contains source chunk p ^ (r & 7), so the GEMM's linear
// global_load_lds staging + XOR-on-read gives 2-way-max (free) ds_read_b128 banks.
__global__ __launch_bounds__(256) void k_im2col(const float* __restrict__ pred,
                                                const float* __restrict__ targ,
                                                u16* __restrict__ Ab, u16* __restrict__ Bb) {
  const int img = blockIdx.y;       // 0..5 : 0-1 pred, 2-5 target
  const int qy  = blockIdx.x;       // 0..45 real rows, 46-47 pad writer
  const int tid = threadIdx.x;
  const bool isA = img < 2;
  const float* image;
  u16* out;
  int rkc = 0;
  if (isA) {
    image = pred + (size_t)img * CC * HW2;
    out = Ab + (size_t)img * MROWS * KK;
  } else {
    int t = img - 2;                // (b*2 + kc)
    rkc = (t & 1) * NPK;
    image = targ + (size_t)t * CC * HW2;
    out = Bb + (size_t)(t >> 1) * NTOT * KK;
  }

  if (qy >= NHW) {                  // zero the 60 pad rows (2116..2175 of this set)
    int p0 = rkc + NQ + (qy - NHW) * 30;
    const u32x4 z = {0u, 0u, 0u, 0u};
    for (int i = tid; i < 30 * 144; i += 256) {
      int rr = i / 144, g = i - rr * 144;
      *reinterpret_cast<u32x4*>(out + ((size_t)(p0 + rr) * KK + g * 8)) = z;
    }
    return;
  }

  __shared__ float sI[CC * 144];    // [c][di*48+x], 73728 B
  __shared__ float sInv[144];

  for (int ch = tid; ch < CC * 36; ch += 256) {   // 36 float4 per channel
    int c = ch / 36, rem = ch - c * 36, di = rem / 12, j = rem - di * 12;
    float4 v = *reinterpret_cast<const float4*>(&image[(size_t)c * HW2 + (qy + di) * WW + j * 4]);
    *reinterpret_cast<float4*>(&sI[c * 144 + di * 48 + j * 4]) = v;
  }
  __syncthreads();
  for (int p = tid; p < 144; p += 256) {
    float s = 0.f;
    for (int c = 0; c < CC; ++c) { float v = sI[c * 144 + p]; s += v * v; }
    sInv[p] = 1.0f / fmaxf(sqrtf(s), 1e-12f);
  }
  __syncthreads();

  const int rb = rkc + qy * NHW;
  for (int g = tid; g < NHW * 144; g += 256) {
    int qx = g / 144, gg = g - qx * 144;
    int r = rb + qx;
    int sc = (gg & ~7) | ((gg & 7) ^ (r & 7));   // pre-swizzled source chunk
    int k0 = sc * 8;
    unsigned pack[4] = {0u, 0u, 0u, 0u};
    #pragma unroll
    for (int e = 0; e < 8; ++e) {
      int k = k0 + e;
      int c = k / 9, s9 = k - 9 * c;
      int di = s9 / 3, dj = s9 - 3 * di;
      int pix = di * 48 + qx + dj;
      float v = sI[c * 144 + pix] * sInv[pix];
      pack[e >> 1] |= ((unsigned)f2bf(v)) << ((e & 1) * 16);
    }
    u32x4 o; o.x = pack[0]; o.y = pack[1]; o.z = pack[2]; o.w = pack[3];
    *reinterpret_cast<u32x4*>(out + ((size_t)r * KK + gg * 8)) = o;
  }
}

// ---- kernel 2: 128x256 bf16 MFMA GEMM, 2-phase/K-tile 8-phase-style pipeline ----
// depth-3 prefetch, counted vmcnt(6) (never 0 in main loop), setprio'd MFMA clusters,
// fused per-row max/argmax epilogue.
__global__ __launch_bounds__(512, 2) void k_gemm(const u16* __restrict__ Ab, const u16* __restrict__ Bb,
                                                 float* __restrict__ valp, int* __restrict__ idxp) {
  __shared__ u16 sA[3][128 * 64];   // 3 x 16 KB
  __shared__ u16 sB[3][256 * 64];   // 3 x 32 KB   (144 KB total, 1 block/CU)

  // XCD-aware bijective swizzle over 578 blocks (q=72, r=2), tm-fastest order
  const int w = blockIdx.x;
  const int xcd = w & 7, pos = w >> 3;
  const int swz = (xcd < 2 ? xcd * 73 : 2 * 73 + (xcd - 2) * 72) + pos;
  const int col = swz / 17;          // 0..33  (b*17 + tn)
  const int tm  = swz - col * 17;    // 0..16
  const int b   = col / 17;
  const int tn  = col - b * 17;

  const int tid = threadIdx.x, lane = tid & 63, wid = tid >> 6;
  const int wm = wid >> 2, wn = wid & 3;          // 2 M-waves x 4 N-waves
  const int r15 = lane & 15, g16 = lane >> 4;

  const u16* Abase = Ab + ((size_t)b * MROWS + (size_t)tm * 128) * KK;
  const u16* Bbase = Bb + ((size_t)b * NTOT + (size_t)tn * 256) * KK;

  // staging: slot s = i*512+tid -> row = s>>3, chunk = s&7 (linear LDS dest s*16B)
  const u16* aSrc[2];
  const u16* bSrc[4];
  #pragma unroll
  for (int i = 0; i < 2; ++i) {
    int s = i * 512 + tid;
    aSrc[i] = Abase + (size_t)(s >> 3) * KK + (s & 7) * 8;
  }
  #pragma unroll
  for (int i = 0; i < 4; ++i) {
    int s = i * 512 + tid;
    bSrc[i] = Bbase + (size_t)(s >> 3) * KK + (s & 7) * 8;
  }

  f32x4 acc[4][4];
  const f32x4 z4 = {0.f, 0.f, 0.f, 0.f};
  #pragma unroll
  for (int i = 0; i < 4; ++i)
    #pragma unroll
    for (int j = 0; j < 4; ++j) acc[i][j] = z4;

  auto stageA = [&](int buf, int kt) {             // 2 loads (A tile half of stage)
    #pragma unroll
    for (int i = 0; i < 2; ++i)
      __builtin_amdgcn_global_load_lds(
        (const __attribute__((address_space(1))) unsigned*)(aSrc[i] + kt * 64),
        (__attribute__((address_space(3))) unsigned*)&sA[buf][(i * 512 + tid) * 8], 16, 0, 0);
    __builtin_amdgcn_global_load_lds(
      (const __attribute__((address_space(1))) unsigned*)(bSrc[0] + kt * 64),
      (__attribute__((address_space(3))) unsigned*)&sB[buf][tid * 8], 16, 0, 0);
  };
  auto stageB = [&](int buf, int kt) {             // remaining 3 B loads
    #pragma unroll
    for (int i = 1; i < 4; ++i)
      __builtin_amdgcn_global_load_lds(
        (const __attribute__((address_space(1))) unsigned*)(bSrc[i] + kt * 64),
        (__attribute__((address_space(3))) unsigned*)&sB[buf][(i * 512 + tid) * 8], 16, 0, 0);
  };

  const int arow0 = wm * 64 + r15;                 // + mi*16
  const int brow0 = wn * 64 + r15;                 // + ni*16

  short8 bfv[4][2];                                // B frags held across both phases
  short8 af01[2][2], af23[2][2];

  auto ldsoff = [&](int row, int kc) { return row * 64 + ((kc ^ (row & 7)) * 8); };

  stageA(0, 0); stageB(0, 0);
  stageA(1, 1); stageB(1, 1);
  asm volatile("s_waitcnt vmcnt(6)" ::: "memory"); // tile 0 landed (own 6 oldest)
  __builtin_amdgcn_s_barrier();                    // everyone's tile-0 loads landed

  int buf = 0;
  for (int kt = 0; kt < NKT; ++kt) {
    // ---- phase A: read A(mi 0,1) + all B frags; stage first half of kt+2 ----
    #pragma unroll
    for (int mi = 0; mi < 2; ++mi)
      #pragma unroll
      for (int ks = 0; ks < 2; ++ks)
        af01[mi][ks] = *reinterpret_cast<const short8*>(&sA[buf][ldsoff(arow0 + mi * 16, ks * 4 + g16)]);
    #pragma unroll
    for (int ni = 0; ni < 4; ++ni)
      #pragma unroll
      for (int ks = 0; ks < 2; ++ks)
        bfv[ni][ks] = *reinterpret_cast<const short8*>(&sB[buf][ldsoff(brow0 + ni * 16, ks * 4 + g16)]);
    int nb = buf + 2; if (nb >= 3) nb -= 3;
    if (kt + 2 < NKT) stageA(nb, kt + 2);
    __builtin_amdgcn_s_barrier();
    asm volatile("s_waitcnt lgkmcnt(0)" ::: "memory");
    __builtin_amdgcn_s_setprio(1);
    #pragma unroll
    for (int ks = 0; ks < 2; ++ks)
      #pragma unroll
      for (int mi = 0; mi < 2; ++mi)
        #pragma unroll
        for (int ni = 0; ni < 4; ++ni)
          acc[mi][ni] = __builtin_amdgcn_mfma_f32_16x16x32_bf16(af01[mi][ks], bfv[ni][ks], acc[mi][ni], 0, 0, 0);
    __builtin_amdgcn_s_setprio(0);
    __builtin_amdgcn_s_barrier();

    // ---- phase B: read A(mi 2,3), reuse B frags; stage second half of kt+2 ----
    #pragma unroll
    for (int mi = 0; mi < 2; ++mi)
      #pragma unroll
      for (int ks = 0; ks < 2; ++ks)
        af23[mi][ks] = *reinterpret_cast<const short8*>(&sA[buf][ldsoff(arow0 + (mi + 2) * 16, ks * 4 + g16)]);
    if (kt + 2 < NKT) stageB(nb, kt + 2);
    __builtin_amdgcn_s_barrier();
    asm volatile("s_waitcnt lgkmcnt(0)" ::: "memory");
    __builtin_amdgcn_s_setprio(1);
    #pragma unroll
    for (int ks = 0; ks < 2; ++ks)
      #pragma unroll
      for (int mi = 0; mi < 2; ++mi)
        #pragma unroll
        for (int ni = 0; ni < 4; ++ni)
          acc[mi + 2][ni] = __builtin_amdgcn_mfma_f32_16x16x32_bf16(af23[mi][ks], bfv[ni][ks], acc[mi + 2][ni], 0, 0, 0);
    __builtin_amdgcn_s_setprio(0);

    // ---- tile boundary: wait for next tile's loads (counted, no drain) ----
    if (kt < NKT - 2) {
      asm volatile("s_waitcnt vmcnt(6)" ::: "memory");   // tile kt+1 landed, kt+2 in flight
      __builtin_amdgcn_s_barrier();
    } else if (kt == NKT - 2) {
      asm volatile("s_waitcnt vmcnt(0)" ::: "memory");   // final drain: tile 17 landed
      __builtin_amdgcn_s_barrier();
    }
    if (++buf == 3) buf = 0;
  }

  // fused epilogue: per row, max + first-wins argmax over this wave's 64 columns
  const int nb0 = tn * 256 + wn * 64;
  #pragma unroll
  for (int mi = 0; mi < 4; ++mi) {
    #pragma unroll
    for (int reg = 0; reg < 4; ++reg) {
      float bv = -3.0e38f; int bi = 0x7fffffff;
      #pragma unroll
      for (int ni = 0; ni < 4; ++ni) {
        int n = nb0 + ni * 16 + r15;
        int ns = n - (n >= NPK ? NPK : 0);
        float v = acc[mi][ni][reg];
        if (ns >= NQ) v = -3.0e38f;                    // mask pad columns
        bool take = (v > bv) || (v == bv && n < bi);
        bv = take ? v : bv;
        bi = take ? n : bi;
      }
      #pragma unroll
      for (int off = 1; off < 16; off <<= 1) {
        float ov = __shfl_xor(bv, off, 64);
        int   oi = __shfl_xor(bi, off, 64);
        bool take = (ov > bv) || (ov == bv && oi < bi);
        bv = take ? ov : bv;
        bi = take ? oi : bi;
      }
      if (r15 == 0) {
        int q = tm * 128 + wm * 64 + mi * 16 + g16 * 4 + reg;
        size_t o = ((size_t)b * MROWS + q) * NHALF + (tn * 4 + wn);
        valp[o] = bv;
        idxp[o] = bi;
      }
    }
  }
}

// ---- kernel 3: wave-per-query argmax over 68 halves + raw-patch MSE ----
__global__ __launch_bounds__(256) void k_msearg(const float* __restrict__ pred, const float* __restrict__ targ,
                                                const float* __restrict__ valp, const int* __restrict__ idxp,
                                                float* __restrict__ msep) {
  int gw = (blockIdx.x * 256 + threadIdx.x) >> 6;
  int lane = threadIdx.x & 63;
  if (gw >= BATCH * NQ) return;
  int b = gw >= NQ ? 1 : 0;
  int q = gw - b * NQ;

  const float* vp = valp + ((size_t)b * MROWS + q) * NHALF;
  const int*   ip = idxp + ((size_t)b * MROWS + q) * NHALF;
  float bv = vp[lane];
  int   bi = ip[lane];
  if (lane < NHALF - 64) {
    float v1 = vp[64 + lane];
    int   i1 = ip[64 + lane];
    if (v1 > bv || (v1 == bv && i1 < bi)) { bv = v1; bi = i1; }
  }
  #pragma unroll
  for (int off = 1; off < 64; off <<= 1) {
    float ov = __shfl_xor(bv, off, 64);
    int   oi = __shfl_xor(bi, off, 64);
    bool take = (ov > bv) || (ov == bv && oi < bi);
    bv = take ? ov : bv;
    bi = take ? oi : bi;
  }
  int n = bi;
  int kc = n >= NPK ? 1 : 0;
  int ns = n - kc * NPK;
  ns = ns < NQ ? ns : NQ - 1;

  int qy = q / NHW, qx = q - qy * NHW;
  int ny = ns / NHW, nx = ns - ny * NHW;
  const float* P = pred + (size_t)b * CC * HW2;
  const float* T = targ + (size_t)(b * 2 + kc) * CC * HW2;
  float s = 0.f;
  for (int i = lane; i < CC * 9; i += 64) {
    int c = i / 9, sp = i - 9 * c;
    int di = sp / 3, dj = sp - 3 * di;
    float d = P[(size_t)c * HW2 + (qy + di) * WW + qx + dj]
            - T[(size_t)c * HW2 + (ny + di) * WW + nx + dj];
    s += d * d;
  }
  #pragma unroll
  for (int off = 1; off < 64; off <<= 1) s += __shfl_xor(s, off, 64);
  if (lane == 0) msep[gw] = s;
}

// ---- kernel 4: final deterministic reduction ----
__global__ void k_final(const float* __restrict__ msep, float* __restrict__ out) {
  int t = threadIdx.x;
  float s = 0.f;
  for (int i = t; i < BATCH * NQ; i += 256) s += msep[i];
  __shared__ float red[256];
  red[t] = s; __syncthreads();
  for (int st = 128; st > 0; st >>= 1) { if (t < st) red[t] += red[t + st]; __syncthreads(); }
  if (t == 0) out[0] = red[0] * (1.0f / 4875264.0f);   // 2*2116*128*9
}

extern "C" void kernel_launch(void* const* d_in, const int* in_sizes, int n_in,
                              void* d_out, int out_size, void* d_ws, size_t ws_size,
                              hipStream_t stream) {
  const float* pred = (const float*)d_in[0];
  const float* targ = (const float*)d_in[1];
  char* ws = (char*)d_ws;

  size_t offA = 0;
  size_t offB = offA + (size_t)BATCH * MROWS * KK * 2;      // 10,027,008
  size_t offV = offB + (size_t)BATCH * NTOT * KK * 2;       // 20,054,016
  size_t offI = offV + (size_t)BATCH * MROWS * NHALF * 4;   // 1,183,744
  size_t offM = offI + (size_t)BATCH * MROWS * NHALF * 4;   // 1,183,744

  u16*   Ab   = (u16*)(ws + offA);
  u16*   Bb   = (u16*)(ws + offB);
  float* valp = (float*)(ws + offV);
  int*   idxp = (int*)(ws + offI);
  float* msep = (float*)(ws + offM);

  k_im2col<<<dim3(48, 6), 256, 0, stream>>>(pred, targ, Ab, Bb);
  k_gemm<<<dim3(578), 512, 0, stream>>>(Ab, Bb, valp, idxp);
  k_msearg<<<dim3((BATCH * NQ + 3) / 4), 256, 0, stream>>>(pred, targ, valp, idxp, msep);
  k_final<<<1, 256, 0, stream>>>(msep, (float*)d_out);
}